// Round 1
// baseline (2711.710 us; speedup 1.0000x reference)
//
#include <hip/hip_runtime.h>

#define NN 65536   // nodes per branch
#define NE 524288  // edges per branch
#define NR 8       // relations
#define NB 256     // graphs
#define DD 128     // feature dim (in == hidden == 128)

// ---------------------------------------------------------------------------
// C[z] = A @ W[z] (+bias). A: [NN][128] row-major, W: [z][128][128], C: [z][NN][128]
// 128x128 tile per block, 256 threads, 8x8 per thread, BK=16.
// ---------------------------------------------------------------------------
__global__ __launch_bounds__(256) void gemm_k128(
    const float* __restrict__ A, const float* __restrict__ Wb,
    float* __restrict__ Cb, const float* __restrict__ bias)
{
  const int zi = blockIdx.z;
  const float* __restrict__ W = Wb + (size_t)zi * DD * DD;
  float* __restrict__ C = Cb + (size_t)zi * NN * DD;
  const int r0 = blockIdx.x * 128;
  __shared__ float As[16][128];  // [k][row] (transposed for vector reads)
  __shared__ float Bs[16][128];  // [k][col]
  const int tid = threadIdx.x;
  const int tx = tid & 15, ty = tid >> 4;
  float acc[8][8];
#pragma unroll
  for (int i = 0; i < 8; ++i)
#pragma unroll
    for (int j = 0; j < 8; ++j) acc[i][j] = 0.f;

  for (int k0 = 0; k0 < 128; k0 += 16) {
#pragma unroll
    for (int q = 0; q < 2; ++q) {
      int t = tid + q * 256;                 // 512 float4 of A tile
      int row = t >> 2, c4 = (t & 3) * 4;
      float4 v = *reinterpret_cast<const float4*>(&A[(size_t)(r0 + row) * DD + k0 + c4]);
      As[c4 + 0][row] = v.x; As[c4 + 1][row] = v.y;
      As[c4 + 2][row] = v.z; As[c4 + 3][row] = v.w;
    }
#pragma unroll
    for (int q = 0; q < 2; ++q) {
      int t = tid + q * 256;                 // 512 float4 of W tile
      int kr = t >> 5, c4 = (t & 31) * 4;
      *reinterpret_cast<float4*>(&Bs[kr][c4]) =
          *reinterpret_cast<const float4*>(&W[(size_t)(k0 + kr) * DD + c4]);
    }
    __syncthreads();
#pragma unroll
    for (int k = 0; k < 16; ++k) {
      float a[8], b[8];
      *reinterpret_cast<float4*>(&a[0]) = *reinterpret_cast<const float4*>(&As[k][ty * 8]);
      *reinterpret_cast<float4*>(&a[4]) = *reinterpret_cast<const float4*>(&As[k][ty * 8 + 4]);
      *reinterpret_cast<float4*>(&b[0]) = *reinterpret_cast<const float4*>(&Bs[k][tx * 8]);
      *reinterpret_cast<float4*>(&b[4]) = *reinterpret_cast<const float4*>(&Bs[k][tx * 8 + 4]);
#pragma unroll
      for (int i = 0; i < 8; ++i)
#pragma unroll
        for (int j = 0; j < 8; ++j)
          acc[i][j] = fmaf(a[i], b[j], acc[i][j]);
    }
    __syncthreads();
  }
#pragma unroll
  for (int i = 0; i < 8; ++i) {
    const size_t row = (size_t)(r0 + ty * 8 + i);
#pragma unroll
    for (int j4 = 0; j4 < 2; ++j4) {
      float4 v;
      v.x = acc[i][j4 * 4 + 0]; v.y = acc[i][j4 * 4 + 1];
      v.z = acc[i][j4 * 4 + 2]; v.w = acc[i][j4 * 4 + 3];
      if (bias) {
        v.x += bias[tx * 8 + j4 * 4 + 0];
        v.y += bias[tx * 8 + j4 * 4 + 1];
        v.z += bias[tx * 8 + j4 * 4 + 2];
        v.w += bias[tx * 8 + j4 * 4 + 3];
      }
      *reinterpret_cast<float4*>(&C[row * DD + tx * 8 + j4 * 4]) = v;
    }
  }
}

// cnt[r*NN + dst] += 1 per edge
__global__ void count_edges(const int* __restrict__ et, const int* __restrict__ dst,
                            float* __restrict__ cnt)
{
  for (int i = blockIdx.x * blockDim.x + threadIdx.x; i < NE; i += gridDim.x * blockDim.x)
    atomicAdd(&cnt[(size_t)et[i] * NN + dst[i]], 1.0f);
}

// out[dst] += xw[type - r0][src] / cnt[type, dst]  (128 threads per edge, 2 edges/block)
__global__ __launch_bounds__(256) void scatter_edges(
    const int* __restrict__ src, const int* __restrict__ dst, const int* __restrict__ et,
    const float* __restrict__ xw, const float* __restrict__ cnt, float* __restrict__ out,
    int r0, int nrel)
{
  const int t = threadIdx.x & 127;
  const int half = threadIdx.x >> 7;
  for (int e = blockIdx.x * 2 + half; e < NE; e += gridDim.x * 2) {
    int ty = et[e] - r0;
    if ((unsigned)ty >= (unsigned)nrel) continue;
    int s = src[e], d = dst[e];
    float inv = 1.0f / cnt[(size_t)(ty + r0) * NN + d];
    float v = xw[((size_t)ty * NN + s) * DD + t] * inv;
    atomicAdd(&out[(size_t)d * DD + t], v);
  }
}

__global__ void relu_inplace(float* __restrict__ p)
{
  const int n4 = NN * DD / 4;
  for (int i = blockIdx.x * blockDim.x + threadIdx.x; i < n4; i += gridDim.x * blockDim.x) {
    float4 v = reinterpret_cast<float4*>(p)[i];
    v.x = fmaxf(v.x, 0.f); v.y = fmaxf(v.y, 0.f);
    v.z = fmaxf(v.z, 0.f); v.w = fmaxf(v.w, 0.f);
    reinterpret_cast<float4*>(p)[i] = v;
  }
}

// pool[batch[n]] += h[n]; pcnt[batch[n]] += 1   (128 threads per node, 2 nodes/block)
__global__ __launch_bounds__(256) void pool_kernel(
    const float* __restrict__ h, const int* __restrict__ batch,
    float* __restrict__ pool, float* __restrict__ pcnt)
{
  const int t = threadIdx.x & 127;
  const int half = threadIdx.x >> 7;
  for (int n = blockIdx.x * 2 + half; n < NN; n += gridDim.x * 2) {
    int b = batch[n];
    atomicAdd(&pool[(size_t)b * DD + t], h[(size_t)n * DD + t]);
    if (t == 0) atomicAdd(&pcnt[b], 1.0f);
  }
}

__global__ void dnorm_kernel(const float* __restrict__ depth, float* __restrict__ dn)
{
  __shared__ float red[NB];
  const int t = threadIdx.x;
  float d = depth[t];
  red[t] = d;
  __syncthreads();
  for (int s = NB / 2; s > 0; s >>= 1) {
    if (t < s) red[t] += red[t + s];
    __syncthreads();
  }
  float mean = red[0] / (float)NB;
  __syncthreads();
  float df = d - mean;
  red[t] = df * df;
  __syncthreads();
  for (int s = NB / 2; s > 0; s >>= 1) {
    if (t < s) red[t] += red[t + s];
    __syncthreads();
  }
  float stdv = sqrtf(red[0] / (float)NB);
  dn[t] = df / (stdv + 1e-6f);
}

// one block per graph (256 blocks, 128 threads)
__global__ __launch_bounds__(128) void regression_kernel(
    const float* __restrict__ spool, const float* __restrict__ spcnt,
    const float* __restrict__ gpool, const float* __restrict__ gpcnt,
    const float* __restrict__ dn,
    const float* __restrict__ W1, const float* __restrict__ b1,
    const float* __restrict__ W2, const float* __restrict__ b2,
    float* __restrict__ out)
{
  const int b = blockIdx.x;
  const int t = threadIdx.x;
  __shared__ float z[2 * DD + 1];
  __shared__ float red[DD];
  float sc = fmaxf(spcnt[b], 1.0f), gc = fmaxf(gpcnt[b], 1.0f);
  z[t] = spool[(size_t)b * DD + t] / sc;
  z[t + DD] = gpool[(size_t)b * DD + t] / gc;
  if (t == 0) z[2 * DD] = dn[b];
  __syncthreads();
  float acc = b1[t];
  for (int k = 0; k < 2 * DD + 1; ++k)
    acc = fmaf(z[k], W1[(size_t)k * DD + t], acc);
  float h = fmaxf(acc, 0.f);
  red[t] = h * W2[t];
  __syncthreads();
  for (int s = DD / 2; s > 0; s >>= 1) {
    if (t < s) red[t] += red[t + s];
    __syncthreads();
  }
  if (t == 0) out[b] = red[0] + b2[0];
}

extern "C" void kernel_launch(void* const* d_in, const int* in_sizes, int n_in,
                              void* d_out, int out_size, void* d_ws, size_t ws_size,
                              hipStream_t stream)
{
  const float* state_x = (const float*)d_in[0];
  const int*   s_ei    = (const int*)d_in[1];
  const int*   s_et    = (const int*)d_in[2];
  const int*   s_batch = (const int*)d_in[3];
  const float* goal_x  = (const float*)d_in[4];
  const int*   g_ei    = (const int*)d_in[5];
  const int*   g_et    = (const int*)d_in[6];
  const int*   g_batch = (const int*)d_in[7];
  const float* depth   = (const float*)d_in[8];
  const float* sW1 = (const float*)d_in[9];
  const float* sR1 = (const float*)d_in[10];
  const float* sb1 = (const float*)d_in[11];
  const float* sW2 = (const float*)d_in[12];
  const float* sR2 = (const float*)d_in[13];
  const float* sb2 = (const float*)d_in[14];
  const float* gW1 = (const float*)d_in[15];
  const float* gR1 = (const float*)d_in[16];
  const float* gb1 = (const float*)d_in[17];
  const float* gW2 = (const float*)d_in[18];
  const float* gR2 = (const float*)d_in[19];
  const float* gb2 = (const float*)d_in[20];
  const float* rW1 = (const float*)d_in[21];
  const float* rb1 = (const float*)d_in[22];
  const float* rW2 = (const float*)d_in[23];
  const float* rb2 = (const float*)d_in[24];

  char* ws = (char*)d_ws;
  size_t off = 0;
  auto alloc = [&](size_t bytes) -> void* {
    void* p = ws + off;
    off += (bytes + 255) & ~(size_t)255;
    return p;
  };
  float* buf0  = (float*)alloc((size_t)NN * DD * 4);
  float* buf1  = (float*)alloc((size_t)NN * DD * 4);
  float* cnt   = (float*)alloc((size_t)NR * NN * 4);
  float* spool = (float*)alloc((size_t)NB * DD * 4);
  float* spcnt = (float*)alloc((size_t)NB * 4);
  float* gpool = (float*)alloc((size_t)NB * DD * 4);
  float* gpcnt = (float*)alloc((size_t)NB * 4);
  float* dn    = (float*)alloc((size_t)NB * 4);
  size_t avail = (ws_size > off) ? (ws_size - off) / ((size_t)NN * DD * 4) : 1;
  int CH = avail >= 8 ? 8 : avail >= 4 ? 4 : avail >= 2 ? 2 : 1;
  float* xw = (float*)alloc((size_t)CH * NN * DD * 4);

  auto branch = [&](const float* x, const int* ei, const int* et, const int* batch,
                    const float* W1, const float* R1, const float* b1,
                    const float* W2, const float* R2, const float* b2,
                    float* pool, float* pcnt)
  {
    const int* src = ei;
    const int* dst = ei + NE;
    hipMemsetAsync(cnt, 0, (size_t)NR * NN * 4, stream);
    count_edges<<<1024, 256, 0, stream>>>(et, dst, cnt);
    // layer 1: buf0 = x @ R1 + b1 + scatter(mean @ W1)
    gemm_k128<<<dim3(NN / 128, 1, 1), 256, 0, stream>>>(x, R1, buf0, b1);
    for (int r0 = 0; r0 < NR; r0 += CH) {
      gemm_k128<<<dim3(NN / 128, 1, CH), 256, 0, stream>>>(x, W1 + (size_t)r0 * DD * DD, xw, nullptr);
      scatter_edges<<<8192, 256, 0, stream>>>(src, dst, et, xw, cnt, buf0, r0, CH);
    }
    relu_inplace<<<2048, 256, 0, stream>>>(buf0);
    // layer 2: buf1
    gemm_k128<<<dim3(NN / 128, 1, 1), 256, 0, stream>>>(buf0, R2, buf1, b2);
    for (int r0 = 0; r0 < NR; r0 += CH) {
      gemm_k128<<<dim3(NN / 128, 1, CH), 256, 0, stream>>>(buf0, W2 + (size_t)r0 * DD * DD, xw, nullptr);
      scatter_edges<<<8192, 256, 0, stream>>>(src, dst, et, xw, cnt, buf1, r0, CH);
    }
    relu_inplace<<<2048, 256, 0, stream>>>(buf1);
    // pool
    hipMemsetAsync(pool, 0, (size_t)NB * DD * 4, stream);
    hipMemsetAsync(pcnt, 0, (size_t)NB * 4, stream);
    pool_kernel<<<4096, 256, 0, stream>>>(buf1, batch, pool, pcnt);
  };

  branch(state_x, s_ei, s_et, s_batch, sW1, sR1, sb1, sW2, sR2, sb2, spool, spcnt);
  branch(goal_x,  g_ei, g_et, g_batch, gW1, gR1, gb1, gW2, gR2, gb2, gpool, gpcnt);

  dnorm_kernel<<<1, NB, 0, stream>>>(depth, dn);
  regression_kernel<<<NB, DD, 0, stream>>>(spool, spcnt, gpool, gpcnt, dn,
                                           rW1, rb1, rW2, rb2, (float*)d_out);
}

// Round 7
// 1717.116 us; speedup vs baseline: 1.5792x; 1.5792x over previous
//
#include <hip/hip_runtime.h>

#define NN 65536   // nodes per branch
#define NE 524288  // edges per branch
#define NR 8       // relations
#define NB 256     // graphs
#define DD 128     // feature dim

typedef __attribute__((ext_vector_type(8))) short bf16x8;
typedef __attribute__((ext_vector_type(4))) float f32x4;

__device__ __forceinline__ unsigned short f2bf(float f) {
  union { float f; unsigned u; } v; v.f = f;
  unsigned r = v.u + 0x7fffu + ((v.u >> 16) & 1u);
  return (unsigned short)(r >> 16);
}
__device__ __forceinline__ float bf2f(unsigned short u) {
  union { unsigned u; float f; } v; v.u = ((unsigned)u) << 16;
  return v.f;
}

// ---------------------------------------------------------------------------
// Weight prep: out[m][c][k] = bf16(W[m][k][c])  (transpose so B-fragments are
// contiguous in k). grid (16, nmat), 256 threads, 4 elems/thread.
// ---------------------------------------------------------------------------
__global__ void wconv(const float* __restrict__ W, unsigned short* __restrict__ out)
{
  const float* Wm = W + (size_t)blockIdx.y * DD * DD;
  unsigned short* Om = out + (size_t)blockIdx.y * DD * DD;
  int idx = blockIdx.x * 1024 + threadIdx.x * 4;
  int c = idx >> 7, k = idx & 127;
#pragma unroll
  for (int i = 0; i < 4; ++i)
    Om[c * DD + k + i] = f2bf(Wm[(size_t)(k + i) * DD + c]);
}

// fp32 -> split bf16 (hi + lo), optional fused relu. 4 elems/thread.
__global__ void conv_split(const float* __restrict__ in, unsigned short* __restrict__ hi,
                           unsigned short* __restrict__ lo, int relu)
{
  const int n4 = NN * DD / 4;
  for (int i = blockIdx.x * blockDim.x + threadIdx.x; i < n4; i += gridDim.x * blockDim.x) {
    float4 v = reinterpret_cast<const float4*>(in)[i];
    if (relu) {
      v.x = fmaxf(v.x, 0.f); v.y = fmaxf(v.y, 0.f);
      v.z = fmaxf(v.z, 0.f); v.w = fmaxf(v.w, 0.f);
    }
    unsigned short h0 = f2bf(v.x), h1 = f2bf(v.y), h2 = f2bf(v.z), h3 = f2bf(v.w);
    unsigned short l0 = f2bf(v.x - bf2f(h0)), l1 = f2bf(v.y - bf2f(h1));
    unsigned short l2 = f2bf(v.z - bf2f(h2)), l3 = f2bf(v.w - bf2f(h3));
    uint2 hp, lp;
    hp.x = (unsigned)h0 | ((unsigned)h1 << 16); hp.y = (unsigned)h2 | ((unsigned)h3 << 16);
    lp.x = (unsigned)l0 | ((unsigned)l1 << 16); lp.y = (unsigned)l2 | ((unsigned)l3 << 16);
    reinterpret_cast<uint2*>(hi)[i] = hp;
    reinterpret_cast<uint2*>(lo)[i] = lp;
  }
}

// ---------------------------------------------------------------------------
// C[z] = A @ W[z]. A split bf16 [NN][128]; BT bf16 [z][col][k] (pre-transposed).
// Grid (NN/128, 1, nz), 256 threads = 4 waves, each wave 32 rows x 128 cols.
// No LDS: fragments loaded straight from global (coalesced 16B/lane).
// outbf!=null: write bf16 at z*NN*DD.  else: write fp32 + bias (root path).
// ---------------------------------------------------------------------------
__global__ __launch_bounds__(256) void gemm_mfma(
    const unsigned short* __restrict__ Ahi, const unsigned short* __restrict__ Alo,
    const unsigned short* __restrict__ BT,
    float* __restrict__ outf, unsigned short* __restrict__ outbf,
    const float* __restrict__ bias)
{
  const int z = blockIdx.z;
  const unsigned short* __restrict__ B = BT + (size_t)z * DD * DD;
  const int w = threadIdx.x >> 6;
  const int l = threadIdx.x & 63;
  const int lr = l & 15;
  const int lk = (l >> 4) * 8;
  const int wrow = blockIdx.x * 128 + w * 32;

  f32x4 acc[2][8];
#pragma unroll
  for (int m = 0; m < 2; ++m)
#pragma unroll
    for (int n = 0; n < 8; ++n) acc[m][n] = 0.f;

#pragma unroll
  for (int kk = 0; kk < 128; kk += 32) {
    bf16x8 ah[2], al[2], b[8];
#pragma unroll
    for (int m = 0; m < 2; ++m) {
      size_t ro = (size_t)(wrow + m * 16 + lr) * DD + kk + lk;
      ah[m] = *(const bf16x8*)(Ahi + ro);
      al[m] = *(const bf16x8*)(Alo + ro);
    }
#pragma unroll
    for (int n = 0; n < 8; ++n)
      b[n] = *(const bf16x8*)(B + (size_t)(n * 16 + lr) * DD + kk + lk);
#pragma unroll
    for (int m = 0; m < 2; ++m)
#pragma unroll
      for (int n = 0; n < 8; ++n) {
        acc[m][n] = __builtin_amdgcn_mfma_f32_16x16x32_bf16(ah[m], b[n], acc[m][n], 0, 0, 0);
        acc[m][n] = __builtin_amdgcn_mfma_f32_16x16x32_bf16(al[m], b[n], acc[m][n], 0, 0, 0);
      }
  }

  const int rb = (l >> 4) * 4;   // C/D: col=lane&15, row=(lane>>4)*4+reg
  if (outbf) {
    unsigned short* O = outbf + (size_t)z * NN * DD;
#pragma unroll
    for (int m = 0; m < 2; ++m)
#pragma unroll
      for (int n = 0; n < 8; ++n)
#pragma unroll
        for (int j = 0; j < 4; ++j)
          O[(size_t)(wrow + m * 16 + rb + j) * DD + n * 16 + lr] = f2bf(acc[m][n][j]);
  } else {
#pragma unroll
    for (int m = 0; m < 2; ++m)
#pragma unroll
      for (int n = 0; n < 8; ++n)
#pragma unroll
        for (int j = 0; j < 4; ++j)
          outf[(size_t)(wrow + m * 16 + rb + j) * DD + n * 16 + lr] =
              acc[m][n][j] + bias[n * 16 + lr];
  }
}

// cnt[r*NN + dst] += 1 per edge
__global__ void count_edges(const int* __restrict__ et, const int* __restrict__ dst,
                            float* __restrict__ cnt)
{
  for (int i = blockIdx.x * blockDim.x + threadIdx.x; i < NE; i += gridDim.x * blockDim.x)
    atomicAdd(&cnt[(size_t)et[i] * NN + dst[i]], 1.0f);
}

// cnt -> 1/max(cnt,1) in place
__global__ void inv_cnt(float* __restrict__ cnt)
{
  const int n = NR * NN;
  for (int i = blockIdx.x * blockDim.x + threadIdx.x; i < n; i += gridDim.x * blockDim.x)
    cnt[i] = 1.0f / fmaxf(cnt[i], 1.0f);
}

// out[dst] += bf2f(xw[type-r0][src]) * invc[type,dst]  (128 threads/edge)
__global__ __launch_bounds__(256) void scatter_edges(
    const int* __restrict__ src, const int* __restrict__ dst, const int* __restrict__ et,
    const unsigned short* __restrict__ xw, const float* __restrict__ invc,
    float* __restrict__ out, int r0, int nrel)
{
  const int t = threadIdx.x & 127;
  const int half = threadIdx.x >> 7;
  for (int e = blockIdx.x * 2 + half; e < NE; e += gridDim.x * 2) {
    int ty = et[e] - r0;
    if ((unsigned)ty >= (unsigned)nrel) continue;
    int s = src[e], d = dst[e];
    float inv = invc[(size_t)(ty + r0) * NN + d];
    float v = bf2f(xw[((size_t)ty * NN + s) * DD + t]) * inv;
    atomicAdd(&out[(size_t)d * DD + t], v);
  }
}

// Sorted-segment mean-pool with fused relu: each block owns 32 consecutive
// nodes, thread t owns feature t; flush one atomic per graph transition.
__global__ __launch_bounds__(128) void pool_seg(
    const float* __restrict__ h, const int* __restrict__ batch,
    float* __restrict__ pool, float* __restrict__ pcnt)
{
  const int t = threadIdx.x;
  const int n0 = blockIdx.x * 32;
  float acc = 0.f;
  int cur = batch[n0];
  int run = 0;
  for (int i = 0; i < 32; ++i) {
    int n = n0 + i;
    int b = batch[n];
    float v = fmaxf(h[(size_t)n * DD + t], 0.f);
    if (b != cur) {
      atomicAdd(&pool[(size_t)cur * DD + t], acc);
      if (t == 0) atomicAdd(&pcnt[cur], (float)run);
      acc = 0.f; run = 0; cur = b;
    }
    acc += v; run += 1;
  }
  atomicAdd(&pool[(size_t)cur * DD + t], acc);
  if (t == 0) atomicAdd(&pcnt[cur], (float)run);
}

__global__ void dnorm_kernel(const float* __restrict__ depth, float* __restrict__ dn)
{
  __shared__ float red[NB];
  const int t = threadIdx.x;
  float d = depth[t];
  red[t] = d;
  __syncthreads();
  for (int s = NB / 2; s > 0; s >>= 1) {
    if (t < s) red[t] += red[t + s];
    __syncthreads();
  }
  float mean = red[0] / (float)NB;
  __syncthreads();
  float df = d - mean;
  red[t] = df * df;
  __syncthreads();
  for (int s = NB / 2; s > 0; s >>= 1) {
    if (t < s) red[t] += red[t + s];
    __syncthreads();
  }
  float stdv = sqrtf(red[0] / (float)NB);
  dn[t] = df / (stdv + 1e-6f);
}

__global__ __launch_bounds__(128) void regression_kernel(
    const float* __restrict__ spool, const float* __restrict__ spcnt,
    const float* __restrict__ gpool, const float* __restrict__ gpcnt,
    const float* __restrict__ dn,
    const float* __restrict__ W1, const float* __restrict__ b1,
    const float* __restrict__ W2, const float* __restrict__ b2,
    float* __restrict__ out)
{
  const int b = blockIdx.x;
  const int t = threadIdx.x;
  __shared__ float z[2 * DD + 1];
  __shared__ float red[DD];
  float sc = fmaxf(spcnt[b], 1.0f), gc = fmaxf(gpcnt[b], 1.0f);
  z[t] = spool[(size_t)b * DD + t] / sc;
  z[t + DD] = gpool[(size_t)b * DD + t] / gc;
  if (t == 0) z[2 * DD] = dn[b];
  __syncthreads();
  float acc = b1[t];
  for (int k = 0; k < 2 * DD + 1; ++k)
    acc = fmaf(z[k], W1[(size_t)k * DD + t], acc);
  float h = fmaxf(acc, 0.f);
  red[t] = h * W2[t];
  __syncthreads();
  for (int s = DD / 2; s > 0; s >>= 1) {
    if (t < s) red[t] += red[t + s];
    __syncthreads();
  }
  if (t == 0) out[b] = red[0] + b2[0];
}

extern "C" void kernel_launch(void* const* d_in, const int* in_sizes, int n_in,
                              void* d_out, int out_size, void* d_ws, size_t ws_size,
                              hipStream_t stream)
{
  const float* state_x = (const float*)d_in[0];
  const int*   s_ei    = (const int*)d_in[1];
  const int*   s_et    = (const int*)d_in[2];
  const int*   s_batch = (const int*)d_in[3];
  const float* goal_x  = (const float*)d_in[4];
  const int*   g_ei    = (const int*)d_in[5];
  const int*   g_et    = (const int*)d_in[6];
  const int*   g_batch = (const int*)d_in[7];
  const float* depth   = (const float*)d_in[8];
  const float* sW1 = (const float*)d_in[9];
  const float* sR1 = (const float*)d_in[10];
  const float* sb1 = (const float*)d_in[11];
  const float* sW2 = (const float*)d_in[12];
  const float* sR2 = (const float*)d_in[13];
  const float* sb2 = (const float*)d_in[14];
  const float* gW1 = (const float*)d_in[15];
  const float* gR1 = (const float*)d_in[16];
  const float* gb1 = (const float*)d_in[17];
  const float* gW2 = (const float*)d_in[18];
  const float* gR2 = (const float*)d_in[19];
  const float* gb2 = (const float*)d_in[20];
  const float* rW1 = (const float*)d_in[21];
  const float* rb1 = (const float*)d_in[22];
  const float* rW2 = (const float*)d_in[23];
  const float* rb2 = (const float*)d_in[24];

  char* ws = (char*)d_ws;
  size_t off = 0;
  auto alloc = [&](size_t bytes) -> void* {
    void* p = ws + off;
    off += (bytes + 255) & ~(size_t)255;
    return p;
  };
  float* buf0   = (float*)alloc((size_t)NN * DD * 4);
  float* buf1   = (float*)alloc((size_t)NN * DD * 4);
  float* cnt    = (float*)alloc((size_t)NR * NN * 4);
  unsigned short* wbfT = (unsigned short*)alloc((size_t)36 * DD * DD * 2);
  unsigned short* xhi  = (unsigned short*)alloc((size_t)NN * DD * 2);
  unsigned short* xlo  = (unsigned short*)alloc((size_t)NN * DD * 2);
  float* spool = (float*)alloc((size_t)NB * DD * 4);
  float* spcnt = (float*)alloc((size_t)NB * 4);
  float* gpool = (float*)alloc((size_t)NB * DD * 4);
  float* gpcnt = (float*)alloc((size_t)NB * 4);
  float* dn    = (float*)alloc((size_t)NB * 4);
  size_t chunk_bytes = (size_t)NN * DD * 2;
  size_t avail = (ws_size > off) ? (ws_size - off) / chunk_bytes : 1;
  int CH = avail >= 8 ? 8 : avail >= 4 ? 4 : avail >= 2 ? 2 : 1;
  unsigned short* xw = (unsigned short*)alloc((size_t)CH * chunk_bytes);

  // weight prep: bf16 + transpose into wbfT[36][128][128]
  // layout: 0-7 sW1, 8 sR1, 9-16 sW2, 17 sR2, 18-25 gW1, 26 gR1, 27-34 gW2, 35 gR2
  wconv<<<dim3(16, 8), 256, 0, stream>>>(sW1, wbfT + (size_t)0 * DD * DD);
  wconv<<<dim3(16, 1), 256, 0, stream>>>(sR1, wbfT + (size_t)8 * DD * DD);
  wconv<<<dim3(16, 8), 256, 0, stream>>>(sW2, wbfT + (size_t)9 * DD * DD);
  wconv<<<dim3(16, 1), 256, 0, stream>>>(sR2, wbfT + (size_t)17 * DD * DD);
  wconv<<<dim3(16, 8), 256, 0, stream>>>(gW1, wbfT + (size_t)18 * DD * DD);
  wconv<<<dim3(16, 1), 256, 0, stream>>>(gR1, wbfT + (size_t)26 * DD * DD);
  wconv<<<dim3(16, 8), 256, 0, stream>>>(gW2, wbfT + (size_t)27 * DD * DD);
  wconv<<<dim3(16, 1), 256, 0, stream>>>(gR2, wbfT + (size_t)35 * DD * DD);

  auto branch = [&](const float* x, const int* ei, const int* et, const int* batch,
                    int wrel1, int wroot1, const float* b1,
                    int wrel2, int wroot2, const float* b2,
                    float* pool, float* pcnt)
  {
    const int* src = ei;
    const int* dst = ei + NE;
    hipMemsetAsync(cnt, 0, (size_t)NR * NN * 4, stream);
    count_edges<<<1024, 256, 0, stream>>>(et, dst, cnt);
    inv_cnt<<<1024, 256, 0, stream>>>(cnt);

    // layer 1
    conv_split<<<2048, 256, 0, stream>>>(x, xhi, xlo, 0);
    gemm_mfma<<<dim3(NN / 128, 1, 1), 256, 0, stream>>>(
        xhi, xlo, wbfT + (size_t)wroot1 * DD * DD, buf0, nullptr, b1);
    for (int r0 = 0; r0 < NR; r0 += CH) {
      gemm_mfma<<<dim3(NN / 128, 1, CH), 256, 0, stream>>>(
          xhi, xlo, wbfT + (size_t)(wrel1 + r0) * DD * DD, nullptr, xw, nullptr);
      scatter_edges<<<8192, 256, 0, stream>>>(src, dst, et, xw, cnt, buf0, r0, CH);
    }
    // layer 2 (relu fused into conv_split)
    conv_split<<<2048, 256, 0, stream>>>(buf0, xhi, xlo, 1);
    gemm_mfma<<<dim3(NN / 128, 1, 1), 256, 0, stream>>>(
        xhi, xlo, wbfT + (size_t)wroot2 * DD * DD, buf1, nullptr, b2);
    for (int r0 = 0; r0 < NR; r0 += CH) {
      gemm_mfma<<<dim3(NN / 128, 1, CH), 256, 0, stream>>>(
          xhi, xlo, wbfT + (size_t)(wrel2 + r0) * DD * DD, nullptr, xw, nullptr);
      scatter_edges<<<8192, 256, 0, stream>>>(src, dst, et, xw, cnt, buf1, r0, CH);
    }
    // mean-pool (relu fused)
    hipMemsetAsync(pool, 0, (size_t)NB * DD * 4, stream);
    hipMemsetAsync(pcnt, 0, (size_t)NB * 4, stream);
    pool_seg<<<NN / 32, 128, 0, stream>>>(buf1, batch, pool, pcnt);
  };

  branch(state_x, s_ei, s_et, s_batch, 0, 8, sb1, 9, 17, sb2, spool, spcnt);
  branch(goal_x,  g_ei, g_et, g_batch, 18, 26, gb1, 27, 35, gb2, gpool, gpcnt);

  dnorm_kernel<<<1, NB, 0, stream>>>(depth, dn);
  regression_kernel<<<NB, DD, 0, stream>>>(spool, spcnt, gpool, gpcnt, dn,
                                           rW1, rb1, rW2, rb2, (float*)d_out);
}

// Round 8
// 1085.865 us; speedup vs baseline: 2.4973x; 1.5813x over previous
//
#include <hip/hip_runtime.h>

#define NN 65536   // nodes per branch
#define NE 524288  // edges per branch
#define NR 8       // relations
#define NB 256     // graphs
#define DD 128     // feature dim

typedef __attribute__((ext_vector_type(8))) short bf16x8;
typedef __attribute__((ext_vector_type(4))) float f32x4;

__device__ __forceinline__ unsigned short f2bf(float f) {
  union { float f; unsigned u; } v; v.f = f;
  unsigned r = v.u + 0x7fffu + ((v.u >> 16) & 1u);
  return (unsigned short)(r >> 16);
}
__device__ __forceinline__ float bf2f(unsigned short u) {
  union { unsigned u; float f; } v; v.u = ((unsigned)u) << 16;
  return v.f;
}

// out[m][c][k] = bf16(W[m][k][c])  (transposed weights)
__global__ void wconv(const float* __restrict__ W, unsigned short* __restrict__ out)
{
  const float* Wm = W + (size_t)blockIdx.y * DD * DD;
  unsigned short* Om = out + (size_t)blockIdx.y * DD * DD;
  int idx = blockIdx.x * 1024 + threadIdx.x * 4;
  int c = idx >> 7, k = idx & 127;
#pragma unroll
  for (int i = 0; i < 4; ++i)
    Om[c * DD + k + i] = f2bf(Wm[(size_t)(k + i) * DD + c]);
}

// fp32 -> split bf16 (hi + lo), optional fused relu
__global__ void conv_split(const float* __restrict__ in, unsigned short* __restrict__ hi,
                           unsigned short* __restrict__ lo, int relu)
{
  const int n4 = NN * DD / 4;
  for (int i = blockIdx.x * blockDim.x + threadIdx.x; i < n4; i += gridDim.x * blockDim.x) {
    float4 v = reinterpret_cast<const float4*>(in)[i];
    if (relu) {
      v.x = fmaxf(v.x, 0.f); v.y = fmaxf(v.y, 0.f);
      v.z = fmaxf(v.z, 0.f); v.w = fmaxf(v.w, 0.f);
    }
    unsigned short h0 = f2bf(v.x), h1 = f2bf(v.y), h2 = f2bf(v.z), h3 = f2bf(v.w);
    unsigned short l0 = f2bf(v.x - bf2f(h0)), l1 = f2bf(v.y - bf2f(h1));
    unsigned short l2 = f2bf(v.z - bf2f(h2)), l3 = f2bf(v.w - bf2f(h3));
    uint2 hp, lp;
    hp.x = (unsigned)h0 | ((unsigned)h1 << 16); hp.y = (unsigned)h2 | ((unsigned)h3 << 16);
    lp.x = (unsigned)l0 | ((unsigned)l1 << 16); lp.y = (unsigned)l2 | ((unsigned)l3 << 16);
    reinterpret_cast<uint2*>(hi)[i] = hp;
    reinterpret_cast<uint2*>(lo)[i] = lp;
  }
}

// ---------------------------------------------------------------------------
// Root GEMM (single matrix): C = A @ W + bias, fp32 out.
// ---------------------------------------------------------------------------
__global__ __launch_bounds__(256) void gemm_mfma(
    const unsigned short* __restrict__ Ahi, const unsigned short* __restrict__ Alo,
    const unsigned short* __restrict__ B,
    float* __restrict__ outf, const float* __restrict__ bias)
{
  const int w = threadIdx.x >> 6;
  const int l = threadIdx.x & 63;
  const int lr = l & 15;
  const int lk = (l >> 4) * 8;
  const int wrow = blockIdx.x * 128 + w * 32;

  f32x4 acc[2][8];
#pragma unroll
  for (int m = 0; m < 2; ++m)
#pragma unroll
    for (int n = 0; n < 8; ++n) acc[m][n] = 0.f;

#pragma unroll
  for (int kk = 0; kk < 128; kk += 32) {
    bf16x8 ah[2], al[2], b[8];
#pragma unroll
    for (int m = 0; m < 2; ++m) {
      size_t ro = (size_t)(wrow + m * 16 + lr) * DD + kk + lk;
      ah[m] = *(const bf16x8*)(Ahi + ro);
      al[m] = *(const bf16x8*)(Alo + ro);
    }
#pragma unroll
    for (int n = 0; n < 8; ++n)
      b[n] = *(const bf16x8*)(B + (size_t)(n * 16 + lr) * DD + kk + lk);
#pragma unroll
    for (int m = 0; m < 2; ++m)
#pragma unroll
      for (int n = 0; n < 8; ++n) {
        acc[m][n] = __builtin_amdgcn_mfma_f32_16x16x32_bf16(ah[m], b[n], acc[m][n], 0, 0, 0);
        acc[m][n] = __builtin_amdgcn_mfma_f32_16x16x32_bf16(al[m], b[n], acc[m][n], 0, 0, 0);
      }
  }
  const int rb = (l >> 4) * 4;
#pragma unroll
  for (int m = 0; m < 2; ++m)
#pragma unroll
    for (int n = 0; n < 8; ++n)
#pragma unroll
      for (int j = 0; j < 4; ++j)
        outf[(size_t)(wrow + m * 16 + rb + j) * DD + n * 16 + lr] =
            acc[m][n][j] + bias[n * 16 + lr];
}

// ---------------------------------------------------------------------------
// Multi-relation GEMM: A fragments held in registers, loop NZ B-matrices.
// Writes NZ bf16 planes. 8x less A traffic than per-z dispatches.
// ---------------------------------------------------------------------------
template<int NZ>
__global__ __launch_bounds__(256) void gemm_mfma_z(
    const unsigned short* __restrict__ Ahi, const unsigned short* __restrict__ Alo,
    const unsigned short* __restrict__ BT, unsigned short* __restrict__ outbf)
{
  const int w = threadIdx.x >> 6;
  const int l = threadIdx.x & 63;
  const int lr = l & 15;
  const int lk = (l >> 4) * 8;
  const int wrow = blockIdx.x * 128 + w * 32;
  const int rb = (l >> 4) * 4;

  bf16x8 ah[2][4], al[2][4];
#pragma unroll
  for (int m = 0; m < 2; ++m)
#pragma unroll
    for (int c = 0; c < 4; ++c) {
      size_t ro = (size_t)(wrow + m * 16 + lr) * DD + c * 32 + lk;
      ah[m][c] = *(const bf16x8*)(Ahi + ro);
      al[m][c] = *(const bf16x8*)(Alo + ro);
    }

#pragma unroll 1
  for (int z = 0; z < NZ; ++z) {
    const unsigned short* __restrict__ B = BT + (size_t)z * DD * DD;
    f32x4 acc[2][8];
#pragma unroll
    for (int m = 0; m < 2; ++m)
#pragma unroll
      for (int n = 0; n < 8; ++n) acc[m][n] = 0.f;
#pragma unroll
    for (int c = 0; c < 4; ++c) {
      bf16x8 b[8];
#pragma unroll
      for (int n = 0; n < 8; ++n)
        b[n] = *(const bf16x8*)(B + (size_t)(n * 16 + lr) * DD + c * 32 + lk);
#pragma unroll
      for (int m = 0; m < 2; ++m)
#pragma unroll
        for (int n = 0; n < 8; ++n) {
          acc[m][n] = __builtin_amdgcn_mfma_f32_16x16x32_bf16(ah[m][c], b[n], acc[m][n], 0, 0, 0);
          acc[m][n] = __builtin_amdgcn_mfma_f32_16x16x32_bf16(al[m][c], b[n], acc[m][n], 0, 0, 0);
        }
    }
    unsigned short* O = outbf + (size_t)z * NN * DD;
#pragma unroll
    for (int m = 0; m < 2; ++m)
#pragma unroll
      for (int n = 0; n < 8; ++n)
#pragma unroll
        for (int j = 0; j < 4; ++j)
          O[(size_t)(wrow + m * 16 + rb + j) * DD + n * 16 + lr] = f2bf(acc[m][n][j]);
  }
}

// cnt[r*NN + dst] += 1 per edge
__global__ void count_edges(const int* __restrict__ et, const int* __restrict__ dst,
                            float* __restrict__ cnt)
{
  for (int i = blockIdx.x * blockDim.x + threadIdx.x; i < NE; i += gridDim.x * blockDim.x)
    atomicAdd(&cnt[(size_t)et[i] * NN + dst[i]], 1.0f);
}

__global__ void inv_cnt(float* __restrict__ cnt)
{
  const int n = NR * NN;
  for (int i = blockIdx.x * blockDim.x + threadIdx.x; i < n; i += gridDim.x * blockDim.x)
    cnt[i] = 1.0f / fmaxf(cnt[i], 1.0f);
}

// --------------------------- CSR build (by dst) ----------------------------
__global__ void hist_edges(const int* __restrict__ dst, int* __restrict__ hist)
{
  for (int i = blockIdx.x * blockDim.x + threadIdx.x; i < NE; i += gridDim.x * blockDim.x)
    atomicAdd(&hist[dst[i]], 1);
}

// exclusive scan of 65536 ints: 256 blocks x 256
__global__ void scan1(const int* __restrict__ hist, int* __restrict__ rowptr,
                      int* __restrict__ bsum)
{
  __shared__ int s[256];
  int i = blockIdx.x * 256 + threadIdx.x;
  int v = hist[i];
  s[threadIdx.x] = v;
  __syncthreads();
  for (int o = 1; o < 256; o <<= 1) {
    int add = (threadIdx.x >= o) ? s[threadIdx.x - o] : 0;
    __syncthreads();
    s[threadIdx.x] += add;
    __syncthreads();
  }
  rowptr[i] = s[threadIdx.x] - v;
  if (threadIdx.x == 255) bsum[blockIdx.x] = s[255];
}

__global__ void scan2(int* __restrict__ bsum, int* __restrict__ boff)
{
  __shared__ int s[256];
  int v = bsum[threadIdx.x];
  s[threadIdx.x] = v;
  __syncthreads();
  for (int o = 1; o < 256; o <<= 1) {
    int add = (threadIdx.x >= o) ? s[threadIdx.x - o] : 0;
    __syncthreads();
    s[threadIdx.x] += add;
    __syncthreads();
  }
  boff[threadIdx.x] = s[threadIdx.x] - v;
}

__global__ void scan3(int* __restrict__ rowptr, const int* __restrict__ boff)
{
  int i = blockIdx.x * 256 + threadIdx.x;
  rowptr[i] += boff[blockIdx.x];
  if (i == NN - 1) rowptr[NN] = NE;
}

// csr[pos] = (rel<<16) | src
__global__ void fill_csr(const int* __restrict__ src, const int* __restrict__ dst,
                         const int* __restrict__ et, const int* __restrict__ rowptr,
                         int* __restrict__ fill, int* __restrict__ csr)
{
  for (int i = blockIdx.x * blockDim.x + threadIdx.x; i < NE; i += gridDim.x * blockDim.x) {
    int d = dst[i];
    int pos = rowptr[d] + atomicAdd(&fill[d], 1);
    csr[pos] = (et[i] << 16) | src[i];
  }
}

// ---------------------------------------------------------------------------
// Gather: one wave per dst row. out[dst] += sum_e xw[rel-r0][src]*invc[rel,dst]
// Non-atomic RMW (exclusive ownership). Thread t holds features 2t, 2t+1.
// ---------------------------------------------------------------------------
__global__ __launch_bounds__(256) void gather_edges(
    const int* __restrict__ csr, const int* __restrict__ rowptr,
    const unsigned* __restrict__ xw2, const float* __restrict__ invc,
    float* __restrict__ out, int r0, int nrel)
{
  const int d = blockIdx.x * 4 + (threadIdx.x >> 6);
  const int t = threadIdx.x & 63;
  const int beg = rowptr[d], end = rowptr[d + 1];
  float a0 = 0.f, a1 = 0.f;
  for (int i = beg; i < end; ++i) {
    int e = csr[i];
    int r = (e >> 16) - r0;
    if ((unsigned)r >= (unsigned)nrel) continue;
    int s = e & 0xFFFF;
    float sc = invc[(size_t)(r + r0) * NN + d];
    unsigned p = xw2[((size_t)r * NN + s) * 64 + t];
    a0 = fmaf(bf2f((unsigned short)(p & 0xFFFFu)), sc, a0);
    a1 = fmaf(bf2f((unsigned short)(p >> 16)), sc, a1);
  }
  float2* o = reinterpret_cast<float2*>(out + (size_t)d * DD + t * 2);
  float2 v = *o;
  v.x += a0; v.y += a1;
  *o = v;
}

// Sorted-segment mean-pool with fused relu
__global__ __launch_bounds__(128) void pool_seg(
    const float* __restrict__ h, const int* __restrict__ batch,
    float* __restrict__ pool, float* __restrict__ pcnt)
{
  const int t = threadIdx.x;
  const int n0 = blockIdx.x * 32;
  float acc = 0.f;
  int cur = batch[n0];
  int run = 0;
  for (int i = 0; i < 32; ++i) {
    int n = n0 + i;
    int b = batch[n];
    float v = fmaxf(h[(size_t)n * DD + t], 0.f);
    if (b != cur) {
      atomicAdd(&pool[(size_t)cur * DD + t], acc);
      if (t == 0) atomicAdd(&pcnt[cur], (float)run);
      acc = 0.f; run = 0; cur = b;
    }
    acc += v; run += 1;
  }
  atomicAdd(&pool[(size_t)cur * DD + t], acc);
  if (t == 0) atomicAdd(&pcnt[cur], (float)run);
}

__global__ void dnorm_kernel(const float* __restrict__ depth, float* __restrict__ dn)
{
  __shared__ float red[NB];
  const int t = threadIdx.x;
  float d = depth[t];
  red[t] = d;
  __syncthreads();
  for (int s = NB / 2; s > 0; s >>= 1) {
    if (t < s) red[t] += red[t + s];
    __syncthreads();
  }
  float mean = red[0] / (float)NB;
  __syncthreads();
  float df = d - mean;
  red[t] = df * df;
  __syncthreads();
  for (int s = NB / 2; s > 0; s >>= 1) {
    if (t < s) red[t] += red[t + s];
    __syncthreads();
  }
  float stdv = sqrtf(red[0] / (float)NB);
  dn[t] = df / (stdv + 1e-6f);
}

__global__ __launch_bounds__(128) void regression_kernel(
    const float* __restrict__ spool, const float* __restrict__ spcnt,
    const float* __restrict__ gpool, const float* __restrict__ gpcnt,
    const float* __restrict__ dn,
    const float* __restrict__ W1, const float* __restrict__ b1,
    const float* __restrict__ W2, const float* __restrict__ b2,
    float* __restrict__ out)
{
  const int b = blockIdx.x;
  const int t = threadIdx.x;
  __shared__ float z[2 * DD + 1];
  __shared__ float red[DD];
  float sc = fmaxf(spcnt[b], 1.0f), gc = fmaxf(gpcnt[b], 1.0f);
  z[t] = spool[(size_t)b * DD + t] / sc;
  z[t + DD] = gpool[(size_t)b * DD + t] / gc;
  if (t == 0) z[2 * DD] = dn[b];
  __syncthreads();
  float acc = b1[t];
  for (int k = 0; k < 2 * DD + 1; ++k)
    acc = fmaf(z[k], W1[(size_t)k * DD + t], acc);
  float h = fmaxf(acc, 0.f);
  red[t] = h * W2[t];
  __syncthreads();
  for (int s = DD / 2; s > 0; s >>= 1) {
    if (t < s) red[t] += red[t + s];
    __syncthreads();
  }
  if (t == 0) out[b] = red[0] + b2[0];
}

extern "C" void kernel_launch(void* const* d_in, const int* in_sizes, int n_in,
                              void* d_out, int out_size, void* d_ws, size_t ws_size,
                              hipStream_t stream)
{
  const float* state_x = (const float*)d_in[0];
  const int*   s_ei    = (const int*)d_in[1];
  const int*   s_et    = (const int*)d_in[2];
  const int*   s_batch = (const int*)d_in[3];
  const float* goal_x  = (const float*)d_in[4];
  const int*   g_ei    = (const int*)d_in[5];
  const int*   g_et    = (const int*)d_in[6];
  const int*   g_batch = (const int*)d_in[7];
  const float* depth   = (const float*)d_in[8];
  const float* sW1 = (const float*)d_in[9];
  const float* sR1 = (const float*)d_in[10];
  const float* sb1 = (const float*)d_in[11];
  const float* sW2 = (const float*)d_in[12];
  const float* sR2 = (const float*)d_in[13];
  const float* sb2 = (const float*)d_in[14];
  const float* gW1 = (const float*)d_in[15];
  const float* gR1 = (const float*)d_in[16];
  const float* gb1 = (const float*)d_in[17];
  const float* gW2 = (const float*)d_in[18];
  const float* gR2 = (const float*)d_in[19];
  const float* gb2 = (const float*)d_in[20];
  const float* rW1 = (const float*)d_in[21];
  const float* rb1 = (const float*)d_in[22];
  const float* rW2 = (const float*)d_in[23];
  const float* rb2 = (const float*)d_in[24];

  char* ws = (char*)d_ws;
  size_t off = 0;
  auto alloc = [&](size_t bytes) -> void* {
    void* p = ws + off;
    off += (bytes + 255) & ~(size_t)255;
    return p;
  };
  float* buf0   = (float*)alloc((size_t)NN * DD * 4);
  float* buf1   = (float*)alloc((size_t)NN * DD * 4);
  float* cnt    = (float*)alloc((size_t)NR * NN * 4);
  unsigned short* wbfT = (unsigned short*)alloc((size_t)36 * DD * DD * 2);
  unsigned short* xhi  = (unsigned short*)alloc((size_t)NN * DD * 2);
  unsigned short* xlo  = (unsigned short*)alloc((size_t)NN * DD * 2);
  float* spool = (float*)alloc((size_t)NB * DD * 4);
  float* spcnt = (float*)alloc((size_t)NB * 4);
  float* gpool = (float*)alloc((size_t)NB * DD * 4);
  float* gpcnt = (float*)alloc((size_t)NB * 4);
  float* dn    = (float*)alloc((size_t)NB * 4);
  int* hist    = (int*)alloc((size_t)NN * 4);
  int* fillc   = (int*)alloc((size_t)NN * 4);
  int* rowptr  = (int*)alloc((size_t)(NN + 1) * 4);
  int* bsum    = (int*)alloc(256 * 4);
  int* boff    = (int*)alloc(256 * 4);
  int* csr     = (int*)alloc((size_t)NE * 4);
  size_t chunk_bytes = (size_t)NN * DD * 2;
  size_t avail = (ws_size > off) ? (ws_size - off) / chunk_bytes : 1;
  int CH = avail >= 8 ? 8 : avail >= 4 ? 4 : avail >= 2 ? 2 : 1;
  unsigned short* xw = (unsigned short*)alloc((size_t)CH * chunk_bytes);

  // weight prep: 0-7 sW1, 8 sR1, 9-16 sW2, 17 sR2, 18-25 gW1, 26 gR1, 27-34 gW2, 35 gR2
  wconv<<<dim3(16, 8), 256, 0, stream>>>(sW1, wbfT + (size_t)0 * DD * DD);
  wconv<<<dim3(16, 1), 256, 0, stream>>>(sR1, wbfT + (size_t)8 * DD * DD);
  wconv<<<dim3(16, 8), 256, 0, stream>>>(sW2, wbfT + (size_t)9 * DD * DD);
  wconv<<<dim3(16, 1), 256, 0, stream>>>(sR2, wbfT + (size_t)17 * DD * DD);
  wconv<<<dim3(16, 8), 256, 0, stream>>>(gW1, wbfT + (size_t)18 * DD * DD);
  wconv<<<dim3(16, 1), 256, 0, stream>>>(gR1, wbfT + (size_t)26 * DD * DD);
  wconv<<<dim3(16, 8), 256, 0, stream>>>(gW2, wbfT + (size_t)27 * DD * DD);
  wconv<<<dim3(16, 1), 256, 0, stream>>>(gR2, wbfT + (size_t)35 * DD * DD);

  auto launch_z = [&](const unsigned short* Bbase, unsigned short* out, int nz) {
    switch (nz) {
      case 8: gemm_mfma_z<8><<<NN / 128, 256, 0, stream>>>(xhi, xlo, Bbase, out); break;
      case 4: gemm_mfma_z<4><<<NN / 128, 256, 0, stream>>>(xhi, xlo, Bbase, out); break;
      case 2: gemm_mfma_z<2><<<NN / 128, 256, 0, stream>>>(xhi, xlo, Bbase, out); break;
      default: gemm_mfma_z<1><<<NN / 128, 256, 0, stream>>>(xhi, xlo, Bbase, out); break;
    }
  };

  auto branch = [&](const float* x, const int* ei, const int* et, const int* batch,
                    int wrel1, int wroot1, const float* b1,
                    int wrel2, int wroot2, const float* b2,
                    float* pool, float* pcnt)
  {
    const int* src = ei;
    const int* dst = ei + NE;
    // CSR by dst (shared by both layers)
    hipMemsetAsync(hist, 0, (size_t)NN * 4, stream);
    hipMemsetAsync(fillc, 0, (size_t)NN * 4, stream);
    hist_edges<<<1024, 256, 0, stream>>>(dst, hist);
    scan1<<<256, 256, 0, stream>>>(hist, rowptr, bsum);
    scan2<<<1, 256, 0, stream>>>(bsum, boff);
    scan3<<<256, 256, 0, stream>>>(rowptr, boff);
    fill_csr<<<1024, 256, 0, stream>>>(src, dst, et, rowptr, fillc, csr);
    // per-(rel,dst) inverse counts
    hipMemsetAsync(cnt, 0, (size_t)NR * NN * 4, stream);
    count_edges<<<1024, 256, 0, stream>>>(et, dst, cnt);
    inv_cnt<<<1024, 256, 0, stream>>>(cnt);

    // layer 1
    conv_split<<<2048, 256, 0, stream>>>(x, xhi, xlo, 0);
    gemm_mfma<<<NN / 128, 256, 0, stream>>>(xhi, xlo, wbfT + (size_t)wroot1 * DD * DD, buf0, b1);
    for (int r0 = 0; r0 < NR; r0 += CH) {
      launch_z(wbfT + (size_t)(wrel1 + r0) * DD * DD, xw, CH);
      gather_edges<<<NN / 4, 256, 0, stream>>>(csr, rowptr, (const unsigned*)xw, cnt, buf0, r0, CH);
    }
    // layer 2 (relu fused into conv_split)
    conv_split<<<2048, 256, 0, stream>>>(buf0, xhi, xlo, 1);
    gemm_mfma<<<NN / 128, 256, 0, stream>>>(xhi, xlo, wbfT + (size_t)wroot2 * DD * DD, buf1, b2);
    for (int r0 = 0; r0 < NR; r0 += CH) {
      launch_z(wbfT + (size_t)(wrel2 + r0) * DD * DD, xw, CH);
      gather_edges<<<NN / 4, 256, 0, stream>>>(csr, rowptr, (const unsigned*)xw, cnt, buf1, r0, CH);
    }
    // mean-pool (relu fused)
    hipMemsetAsync(pool, 0, (size_t)NB * DD * 4, stream);
    hipMemsetAsync(pcnt, 0, (size_t)NB * 4, stream);
    pool_seg<<<NN / 32, 128, 0, stream>>>(buf1, batch, pool, pcnt);
  };

  branch(state_x, s_ei, s_et, s_batch, 0, 8, sb1, 9, 17, sb2, spool, spcnt);
  branch(goal_x,  g_ei, g_et, g_batch, 18, 26, gb1, 27, 35, gb2, gpool, gpcnt);

  dnorm_kernel<<<1, NB, 0, stream>>>(depth, dn);
  regression_kernel<<<NB, DD, 0, stream>>>(spool, spcnt, gpool, gpcnt, dn,
                                           rW1, rb1, rW2, rb2, (float*)d_out);
}